// Round 1
// 726.625 us; speedup vs baseline: 1.0344x; 1.0344x over previous
//
#include <hip/hip_runtime.h>
#include <cmath>

#define Bb 32
#define Dm 4096
#define Hh 32
#define HKVh 8
#define HD 128
#define Gq 4
#define MAXLEN 2048
#define NQ 4096
#define NKV 1024
#define NTOT 6144
#define KSPLIT 8
#define KCH 512
#define LSPLIT 4
#define SCALE 0.08838834764831845f

__device__ __forceinline__ float4 fma4(float s, float4 w, float4 a) {
    a.x = fmaf(s, w.x, a.x); a.y = fmaf(s, w.y, a.y);
    a.z = fmaf(s, w.z, a.z); a.w = fmaf(s, w.w, a.w);
    return a;
}

// ---------- Kernel 1: qkv split-K partial GEMM: part[ks][b][NTOT] ----------
__global__ __launch_bounds__(256) void k_qkv(const float* __restrict__ x,
    const float* __restrict__ wq, const float* __restrict__ wk,
    const float* __restrict__ wv, float* __restrict__ part)
{
    __shared__ float xs[Bb][KCH];   // 64 KB
    const int ct = blockIdx.x;      // 0..95 column tile (64 cols)
    const int ks = blockIdx.y;      // 0..7 k-split
    const int c0 = ct * 64;
    const int k0 = ks * KCH;
    const float* Wp; int ldw; int cw;
    if (c0 < NQ)          { Wp = wq; ldw = NQ;  cw = c0; }
    else if (c0 < NQ+NKV) { Wp = wk; ldw = NKV; cw = c0 - NQ; }
    else                  { Wp = wv; ldw = NKV; cw = c0 - NQ - NKV; }

    const int t = threadIdx.x;
    for (int i = t; i < Bb * (KCH/4); i += 256) {
        int b = i >> 7;
        int kk = (i & 127) << 2;
        float4 v4 = *(const float4*)(x + (size_t)b*Dm + k0 + kk);
        xs[b][kk+0] = v4.x; xs[b][kk+1] = v4.y; xs[b][kk+2] = v4.z; xs[b][kk+3] = v4.w;
    }
    __syncthreads();

    const int cg = t & 15;          // 16 col-groups of 4 cols
    const int bg = t >> 4;          // 16 batch-groups of 2 batches
    const int b0 = bg * 2;
    const float* wp = Wp + (size_t)k0 * ldw + cw + cg*4;
    float4 a0 = make_float4(0.f,0.f,0.f,0.f), a1 = make_float4(0.f,0.f,0.f,0.f);
#pragma unroll 2
    for (int k = 0; k < KCH; k += 4) {
        float4 w0 = *(const float4*)(wp);
        float4 w1 = *(const float4*)(wp + ldw);
        float4 w2 = *(const float4*)(wp + 2*ldw);
        float4 w3 = *(const float4*)(wp + 3*ldw);
        wp += 4*ldw;
        float4 xa = *(const float4*)(&xs[b0][k]);
        float4 xb = *(const float4*)(&xs[b0+1][k]);
        a0 = fma4(xa.x, w0, a0); a1 = fma4(xb.x, w0, a1);
        a0 = fma4(xa.y, w1, a0); a1 = fma4(xb.y, w1, a1);
        a0 = fma4(xa.z, w2, a0); a1 = fma4(xb.z, w2, a1);
        a0 = fma4(xa.w, w3, a0); a1 = fma4(xb.w, w3, a1);
    }
    size_t base = ((size_t)ks * Bb + b0) * NTOT + c0 + cg*4;
    *(float4*)(part + base) = a0;
    *(float4*)(part + base + NTOT) = a1;
}

// ---------- Kernel 2: reduce split-K + RoPE + scatter to caches / qbuf ----------
__global__ __launch_bounds__(256) void k_rope_scatter(const float* __restrict__ part,
    const float* __restrict__ cos_, const float* __restrict__ sin_,
    const int* __restrict__ start_pos, float* __restrict__ qbuf,
    float* __restrict__ cache_k, float* __restrict__ cache_v)
{
    int idx = blockIdx.x*256 + threadIdx.x;   // pair id, 98304 total
    int b  = idx / (NTOT/2);
    int cp = idx % (NTOT/2);
    int c = cp*2;
    float xr = 0.f, xi = 0.f;
#pragma unroll
    for (int s = 0; s < KSPLIT; ++s) {
        const float2 p = *(const float2*)(part + ((size_t)s*Bb + b)*NTOT + c);
        xr += p.x; xi += p.y;
    }
    const int sp = start_pos[0];
    if (c < NQ) {
        int h = c / HD, dd = c % HD; int fi = dd >> 1;
        float co = cos_[fi], si = sin_[fi];
        float2 o = make_float2(xr*co - xi*si, xr*si + xi*co);
        *(float2*)(qbuf + ((size_t)b*Hh + h)*HD + dd) = o;
    } else if (c < NQ+NKV) {
        int cc = c - NQ; int h = cc / HD, dd = cc % HD; int fi = dd >> 1;
        float co = cos_[fi], si = sin_[fi];
        float2 o = make_float2(xr*co - xi*si, xr*si + xi*co);
        *(float2*)(cache_k + (((size_t)b*HKVh + h)*MAXLEN + sp)*HD + dd) = o;
    } else {
        int cc = c - NQ - NKV; int h = cc / HD, dd = cc % HD;
        *(float2*)(cache_v + (((size_t)b*HKVh + h)*MAXLEN + sp)*HD + dd) = make_float2(xr, xi);
    }
}

// ---------- Kernel 3: flash-decode attention, barrier-free per-wave streaming ----------
// grid (256, LSPLIT), block 512 = 8 waves.
// Each wave owns a contiguous 1/8 stripe of this block's L-range and keeps a private
// online-softmax state (m, l, acc) fully in registers. Half-wave (32 lanes) per
// position: float4 K/V loads -> 1 KB per wave-instruction pair, butterfly-reduce dot.
// One __syncthreads at the end to merge the 8 wave partials in LDS.
__global__ __launch_bounds__(512) void k_attn(const float* __restrict__ qbuf,
    const float* __restrict__ cache_k, const float* __restrict__ cache_v,
    const int* __restrict__ start_pos, float* __restrict__ pout)
{
    __shared__ float sm[8][Gq];
    __shared__ float sl[8][Gq];
    __shared__ float sacc[8][Gq][HD];   // 16 KB

    const int bk = blockIdx.x;          // b*8 + kv
    const int b  = bk >> 3;
    const int kv = bk & 7;
    const int sp = blockIdx.y;
    const int L  = start_pos[0] + 1;
    const int per = (L + LSPLIT - 1) / LSPLIT;
    const int p0 = sp * per;
    const int p1 = min(L, p0 + per);

    const int t = threadIdx.x;
    const int wave = t >> 6;
    const int lane = t & 63;
    const int half = lane >> 5;         // which of 2 positions in a pair
    const int dl   = lane & 31;         // d-group: covers d = dl*4 .. dl*4+3

    // q for the 4 grouped heads, pre-scaled by 1/sqrt(HD)
    float4 q4[Gq];
#pragma unroll
    for (int g = 0; g < Gq; ++g) {
        float4 qq = *(const float4*)(qbuf + ((size_t)b*Hh + kv*Gq + g)*HD + dl*4);
        qq.x *= SCALE; qq.y *= SCALE; qq.z *= SCALE; qq.w *= SCALE;
        q4[g] = qq;
    }

    const float* kbase = cache_k + ((size_t)b*HKVh + kv)*MAXLEN*HD;
    const float* vbase = cache_v + ((size_t)b*HKVh + kv)*MAXLEN*HD;

    // this wave's contiguous stripe
    const int nw  = (per + 7) >> 3;
    const int wp0 = p0 + wave * nw;
    const int wp1 = min(p1, wp0 + nw);

    float  m[Gq], l[Gq];
    float4 acc[Gq];
#pragma unroll
    for (int g = 0; g < Gq; ++g) {
        m[g] = -1e30f; l[g] = 0.f;
        acc[g] = make_float4(0.f, 0.f, 0.f, 0.f);
    }

    for (int pp = wp0; pp < wp1; pp += 4) {
        const int pa = pp + half;
        const int pb = pp + 2 + half;
        const bool va = pa < wp1;
        const bool vb = pb < wp1;
        const int pca = va ? pa : wp0;
        const int pcb = vb ? pb : wp0;
        // issue all 4 loads up front (2 K rows + 2 V rows per half -> 4 KB/wave in flight)
        const float4 kA = *(const float4*)(kbase + (size_t)pca*HD + dl*4);
        const float4 kB = *(const float4*)(kbase + (size_t)pcb*HD + dl*4);
        const float4 vA = *(const float4*)(vbase + (size_t)pca*HD + dl*4);
        const float4 vB = *(const float4*)(vbase + (size_t)pcb*HD + dl*4);

        float sA[Gq], sB[Gq];
#pragma unroll
        for (int g = 0; g < Gq; ++g) {
            sA[g] = q4[g].x*kA.x + q4[g].y*kA.y + q4[g].z*kA.z + q4[g].w*kA.w;
            sB[g] = q4[g].x*kB.x + q4[g].y*kB.y + q4[g].z*kB.z + q4[g].w*kB.w;
        }
        // butterfly reduce within each 32-lane half (offsets <32 stay inside the half)
#pragma unroll
        for (int off = 16; off; off >>= 1) {
#pragma unroll
            for (int g = 0; g < Gq; ++g) {
                sA[g] += __shfl_xor(sA[g], off);
                sB[g] += __shfl_xor(sB[g], off);
            }
        }
        if (!va) { sA[0] = -INFINITY; sA[1] = -INFINITY; sA[2] = -INFINITY; sA[3] = -INFINITY; }
        if (!vb) { sB[0] = -INFINITY; sB[1] = -INFINITY; sB[2] = -INFINITY; sB[3] = -INFINITY; }

        // branchless online-softmax update, position A then B
#pragma unroll
        for (int g = 0; g < Gq; ++g) {
            float mn = fmaxf(m[g], sA[g]);
            float al = __expf(m[g] - mn);     // m init -1e30 (finite) => exp(-inf)=0 on first hit
            float e  = __expf(sA[g] - mn);    // invalid pos: exp(-inf - finite) = 0
            m[g] = mn;
            l[g] = l[g]*al + e;
            acc[g].x = fmaf(e, vA.x, acc[g].x*al);
            acc[g].y = fmaf(e, vA.y, acc[g].y*al);
            acc[g].z = fmaf(e, vA.z, acc[g].z*al);
            acc[g].w = fmaf(e, vA.w, acc[g].w*al);
        }
#pragma unroll
        for (int g = 0; g < Gq; ++g) {
            float mn = fmaxf(m[g], sB[g]);
            float al = __expf(m[g] - mn);
            float e  = __expf(sB[g] - mn);
            m[g] = mn;
            l[g] = l[g]*al + e;
            acc[g].x = fmaf(e, vB.x, acc[g].x*al);
            acc[g].y = fmaf(e, vB.y, acc[g].y*al);
            acc[g].z = fmaf(e, vB.z, acc[g].z*al);
            acc[g].w = fmaf(e, vB.w, acc[g].w*al);
        }
    }

    // merge the two half-wave partials (positions were split across halves)
#pragma unroll
    for (int g = 0; g < Gq; ++g) {
        float mo = __shfl_xor(m[g], 32);
        float lo = __shfl_xor(l[g], 32);
        float ax = __shfl_xor(acc[g].x, 32);
        float ay = __shfl_xor(acc[g].y, 32);
        float az = __shfl_xor(acc[g].z, 32);
        float aw = __shfl_xor(acc[g].w, 32);
        float mn = fmaxf(m[g], mo);
        float a0 = __expf(m[g] - mn);
        float a1 = __expf(mo - mn);
        m[g] = mn;
        l[g] = l[g]*a0 + lo*a1;
        acc[g].x = acc[g].x*a0 + ax*a1;
        acc[g].y = acc[g].y*a0 + ay*a1;
        acc[g].z = acc[g].z*a0 + az*a1;
        acc[g].w = acc[g].w*a0 + aw*a1;
    }

    // stash wave partials in LDS (both halves hold identical values; half 0 writes)
    if (half == 0) {
#pragma unroll
        for (int g = 0; g < Gq; ++g) {
            *(float4*)(&sacc[wave][g][dl*4]) = acc[g];
            if (dl == 0) { sm[wave][g] = m[g]; sl[wave][g] = l[g]; }
        }
    }
    __syncthreads();

    // final block combine: 512 threads -> one (g, d) each
    {
        const int g = t >> 7, d = t & 127;
        float M = -1e30f;
#pragma unroll
        for (int w = 0; w < 8; ++w) M = fmaxf(M, sm[w][g]);
        float num = 0.f, den = 0.f;
#pragma unroll
        for (int w = 0; w < 8; ++w) {
            float wt = __expf(sm[w][g] - M);
            num = fmaf(wt, sacc[w][g][d], num);
            den = fmaf(wt, sl[w][g], den);
        }
        float* po = pout + (size_t)(bk * LSPLIT + sp) * (Gq*HD + 2*Gq);
        po[g*HD + d] = num;
        if (d == 0) { po[Gq*HD + g] = M; po[Gq*HD + Gq + g] = den; }
    }
}

// ---------- Kernel 4: combine L-splits -> attn_out [b][h][d] ----------
__global__ __launch_bounds__(256) void k_comb(const float* __restrict__ pout,
    float* __restrict__ attn)
{
    int idx = blockIdx.x*256 + threadIdx.x;   // 131072
    int d = idx & 127;
    int h = (idx >> 7) & 31;
    int b = idx >> 12;
    int kv = h >> 2, g = h & 3;
    int bk = b*8 + kv;
    const float* base = pout + (size_t)bk * LSPLIT * (Gq*HD + 2*Gq);
    float m = -INFINITY;
#pragma unroll
    for (int s = 0; s < LSPLIT; ++s) m = fmaxf(m, base[s*520 + 512 + g]);
    float num = 0.f, den = 0.f;
#pragma unroll
    for (int s = 0; s < LSPLIT; ++s) {
        float ms = base[s*520 + 512 + g];
        float ls = base[s*520 + 516 + g];
        float w = (ms == -INFINITY) ? 0.f : __expf(ms - m);
        num = fmaf(w, base[s*520 + g*HD + d], num);
        den = fmaf(w, ls, den);
    }
    attn[idx] = num / den;
}

// ---------- Kernel 5: out-projection split-K partial: part[ks][b][4096] ----------
__global__ __launch_bounds__(256) void k_proj(const float* __restrict__ inp,
    const float* __restrict__ W, float* __restrict__ part)
{
    __shared__ float xs[Bb][KCH];
    const int ct = blockIdx.x;      // 0..63
    const int ks = blockIdx.y;
    const int c0 = ct * 64;
    const int k0 = ks * KCH;

    const int t = threadIdx.x;
    for (int i = t; i < Bb * (KCH/4); i += 256) {
        int b = i >> 7;
        int kk = (i & 127) << 2;
        float4 v4 = *(const float4*)(inp + (size_t)b*NQ + k0 + kk);
        xs[b][kk+0] = v4.x; xs[b][kk+1] = v4.y; xs[b][kk+2] = v4.z; xs[b][kk+3] = v4.w;
    }
    __syncthreads();

    const int cg = t & 15;
    const int bg = t >> 4;
    const int b0 = bg * 2;
    const float* wp = W + (size_t)k0 * NQ + c0 + cg*4;
    float4 a0 = make_float4(0.f,0.f,0.f,0.f), a1 = make_float4(0.f,0.f,0.f,0.f);
#pragma unroll 2
    for (int k = 0; k < KCH; k += 4) {
        float4 w0 = *(const float4*)(wp);
        float4 w1 = *(const float4*)(wp + NQ);
        float4 w2 = *(const float4*)(wp + 2*NQ);
        float4 w3 = *(const float4*)(wp + 3*NQ);
        wp += 4*NQ;
        float4 xa = *(const float4*)(&xs[b0][k]);
        float4 xb = *(const float4*)(&xs[b0+1][k]);
        a0 = fma4(xa.x, w0, a0); a1 = fma4(xb.x, w0, a1);
        a0 = fma4(xa.y, w1, a0); a1 = fma4(xb.y, w1, a1);
        a0 = fma4(xa.z, w2, a0); a1 = fma4(xb.z, w2, a1);
        a0 = fma4(xa.w, w3, a0); a1 = fma4(xb.w, w3, a1);
    }
    size_t base = ((size_t)ks * Bb + b0) * NQ + c0 + cg*4;
    *(float4*)(part + base) = a0;
    *(float4*)(part + base + NQ) = a1;
}

// ---------- Kernel 6: reduce proj partials -> d_out ----------
__global__ __launch_bounds__(256) void k_red(const float* __restrict__ part,
    float* __restrict__ out)
{
    int idx = blockIdx.x*256 + threadIdx.x;   // 131072
    float s = 0.f;
#pragma unroll
    for (int k = 0; k < KSPLIT; ++k) s += part[(size_t)k*Bb*NQ + idx];
    out[idx] = s;
}

extern "C" void kernel_launch(void* const* d_in, const int* in_sizes, int n_in,
                              void* d_out, int out_size, void* d_ws, size_t ws_size,
                              hipStream_t stream)
{
    const float* x  = (const float*)d_in[0];
    float* cache_k  = (float*)d_in[1];
    float* cache_v  = (float*)d_in[2];
    const float* wq = (const float*)d_in[3];
    const float* wk = (const float*)d_in[4];
    const float* wv = (const float*)d_in[5];
    const float* wo = (const float*)d_in[6];
    const float* fc = (const float*)d_in[7];
    const float* fs = (const float*)d_in[8];
    const int* sp   = (const int*)d_in[9];
    float* out      = (float*)d_out;

    float* ws = (float*)d_ws;
    float* qkv_part = ws;                       // 8*32*6144   = 1572864 f
    float* qbuf     = qkv_part + 1572864;       // 32*32*128   = 131072 f
    float* attn_prt = qbuf + 131072;            // 256*4*520   = 532480 f
    float* attn_out = attn_prt + 532480;        // 131072 f
    float* proj_prt = attn_out + 131072;        // 8*32*4096   = 1048576 f

    k_qkv<<<dim3(96, 8), 256, 0, stream>>>(x, wq, wk, wv, qkv_part);
    k_rope_scatter<<<dim3(384), 256, 0, stream>>>(qkv_part, fc, fs, sp, qbuf, cache_k, cache_v);
    k_attn<<<dim3(256, LSPLIT), 512, 0, stream>>>(qbuf, cache_k, cache_v, sp, attn_prt);
    k_comb<<<dim3(512), 256, 0, stream>>>(attn_prt, attn_out);
    k_proj<<<dim3(64, 8), 256, 0, stream>>>(attn_out, wo, proj_prt);
    k_red<<<dim3(512), 256, 0, stream>>>(proj_prt, out);
}

// Round 2
// 720.222 us; speedup vs baseline: 1.0436x; 1.0089x over previous
//
#include <hip/hip_runtime.h>
#include <cmath>

#define Bb 32
#define Dm 4096
#define Hh 32
#define HKVh 8
#define HD 128
#define Gq 4
#define MAXLEN 2048
#define NQ 4096
#define NKV 1024
#define NTOT 6144
#define KSPLIT 8
#define KCH 512
#define LSPLIT 4
// SCALE * log2(e): scores computed directly in exp2 domain
#define SC2 0.12753102f

__device__ __forceinline__ float4 fma4(float s, float4 w, float4 a) {
    a.x = fmaf(s, w.x, a.x); a.y = fmaf(s, w.y, a.y);
    a.z = fmaf(s, w.z, a.z); a.w = fmaf(s, w.w, a.w);
    return a;
}

__device__ __forceinline__ float fast_exp2(float x) {
#if __has_builtin(__builtin_amdgcn_exp2f)
    return __builtin_amdgcn_exp2f(x);
#else
    return exp2f(x);
#endif
}

// VALU-only butterfly add over 16 lanes (no DS pipe):
// quad_perm(1,0,3,2)=0xB1, quad_perm(2,3,0,1)=0x4E, row_half_mirror=0x141, row_mirror=0x140
#define DPP_ADD(x, ctrl) \
    ((x) + __int_as_float(__builtin_amdgcn_update_dpp(0, __float_as_int(x), (ctrl), 0xf, 0xf, true)))

__device__ __forceinline__ float red16(float x) {
    x = DPP_ADD(x, 0xB1);
    x = DPP_ADD(x, 0x4E);
    x = DPP_ADD(x, 0x141);
    x = DPP_ADD(x, 0x140);
    return x;
}

// ---------- Kernel 1: qkv split-K partial GEMM: part[ks][b][NTOT] ----------
__global__ __launch_bounds__(256) void k_qkv(const float* __restrict__ x,
    const float* __restrict__ wq, const float* __restrict__ wk,
    const float* __restrict__ wv, float* __restrict__ part)
{
    __shared__ float xs[Bb][KCH];   // 64 KB
    const int ct = blockIdx.x;      // 0..95 column tile (64 cols)
    const int ks = blockIdx.y;      // 0..7 k-split
    const int c0 = ct * 64;
    const int k0 = ks * KCH;
    const float* Wp; int ldw; int cw;
    if (c0 < NQ)          { Wp = wq; ldw = NQ;  cw = c0; }
    else if (c0 < NQ+NKV) { Wp = wk; ldw = NKV; cw = c0 - NQ; }
    else                  { Wp = wv; ldw = NKV; cw = c0 - NQ - NKV; }

    const int t = threadIdx.x;
    for (int i = t; i < Bb * (KCH/4); i += 256) {
        int b = i >> 7;
        int kk = (i & 127) << 2;
        float4 v4 = *(const float4*)(x + (size_t)b*Dm + k0 + kk);
        xs[b][kk+0] = v4.x; xs[b][kk+1] = v4.y; xs[b][kk+2] = v4.z; xs[b][kk+3] = v4.w;
    }
    __syncthreads();

    const int cg = t & 15;          // 16 col-groups of 4 cols
    const int bg = t >> 4;          // 16 batch-groups of 2 batches
    const int b0 = bg * 2;
    const float* wp = Wp + (size_t)k0 * ldw + cw + cg*4;
    float4 a0 = make_float4(0.f,0.f,0.f,0.f), a1 = make_float4(0.f,0.f,0.f,0.f);
#pragma unroll 2
    for (int k = 0; k < KCH; k += 4) {
        float4 w0 = *(const float4*)(wp);
        float4 w1 = *(const float4*)(wp + ldw);
        float4 w2 = *(const float4*)(wp + 2*ldw);
        float4 w3 = *(const float4*)(wp + 3*ldw);
        wp += 4*ldw;
        float4 xa = *(const float4*)(&xs[b0][k]);
        float4 xb = *(const float4*)(&xs[b0+1][k]);
        a0 = fma4(xa.x, w0, a0); a1 = fma4(xb.x, w0, a1);
        a0 = fma4(xa.y, w1, a0); a1 = fma4(xb.y, w1, a1);
        a0 = fma4(xa.z, w2, a0); a1 = fma4(xb.z, w2, a1);
        a0 = fma4(xa.w, w3, a0); a1 = fma4(xb.w, w3, a1);
    }
    size_t base = ((size_t)ks * Bb + b0) * NTOT + c0 + cg*4;
    *(float4*)(part + base) = a0;
    *(float4*)(part + base + NTOT) = a1;
}

// ---------- Kernel 2: reduce split-K + RoPE + scatter to caches / qbuf ----------
__global__ __launch_bounds__(256) void k_rope_scatter(const float* __restrict__ part,
    const float* __restrict__ cos_, const float* __restrict__ sin_,
    const int* __restrict__ start_pos, float* __restrict__ qbuf,
    float* __restrict__ cache_k, float* __restrict__ cache_v)
{
    int idx = blockIdx.x*256 + threadIdx.x;   // pair id, 98304 total
    int b  = idx / (NTOT/2);
    int cp = idx % (NTOT/2);
    int c = cp*2;
    float xr = 0.f, xi = 0.f;
#pragma unroll
    for (int s = 0; s < KSPLIT; ++s) {
        const float2 p = *(const float2*)(part + ((size_t)s*Bb + b)*NTOT + c);
        xr += p.x; xi += p.y;
    }
    const int sp = start_pos[0];
    if (c < NQ) {
        int h = c / HD, dd = c % HD; int fi = dd >> 1;
        float co = cos_[fi], si = sin_[fi];
        float2 o = make_float2(xr*co - xi*si, xr*si + xi*co);
        *(float2*)(qbuf + ((size_t)b*Hh + h)*HD + dd) = o;
    } else if (c < NQ+NKV) {
        int cc = c - NQ; int h = cc / HD, dd = cc % HD; int fi = dd >> 1;
        float co = cos_[fi], si = sin_[fi];
        float2 o = make_float2(xr*co - xi*si, xr*si + xi*co);
        *(float2*)(cache_k + (((size_t)b*HKVh + h)*MAXLEN + sp)*HD + dd) = o;
    } else {
        int cc = c - NQ - NKV; int h = cc / HD, dd = cc % HD;
        *(float2*)(cache_v + (((size_t)b*HKVh + h)*MAXLEN + sp)*HD + dd) = make_float2(xr, xi);
    }
}

// ---------- Kernel 3: flash-decode attention, DPP-reduce streaming ----------
// grid (256, LSPLIT), block 512 = 8 waves. Each wave owns a contiguous stripe.
// Lane layout: sg = lane>>4 selects 1 of 4 concurrent positions; dl = lane&15
// owns d = dl*4..+3 and 64+dl*4..+3 (two float4 per K/V row, 16 lanes per row).
// QK^T dot reduced with a 4-step DPP butterfly (pure VALU, zero DS ops).
// Each 16-lane group keeps private online-softmax state (m, l, acc[8]) in regs;
// merged across groups via 2 shfl butterflies at the end, then across waves in LDS.
// All exponentials in exp2 domain (scores pre-scaled by 1/sqrt(HD)*log2e).
__global__ __launch_bounds__(512) void k_attn(const float* __restrict__ qbuf,
    const float* __restrict__ cache_k, const float* __restrict__ cache_v,
    const int* __restrict__ start_pos, float* __restrict__ pout)
{
    __shared__ float sm[8][Gq];
    __shared__ float sl[8][Gq];
    __shared__ float sacc[8][Gq][HD];   // 16 KB

    const int bk = blockIdx.x;          // b*8 + kv
    const int b  = bk >> 3;
    const int kv = bk & 7;
    const int sp = blockIdx.y;
    const int L  = start_pos[0] + 1;
    const int per = (L + LSPLIT - 1) / LSPLIT;
    const int p0 = sp * per;
    const int p1 = min(L, p0 + per);

    const int t = threadIdx.x;
    const int wave = t >> 6;
    const int lane = t & 63;
    const int sg   = lane >> 4;         // position subgroup 0..3
    const int dl   = lane & 15;         // d-slice within a row

    // q fragments for the 4 grouped heads, pre-scaled into exp2 domain
    float4 qa[Gq], qb[Gq];
#pragma unroll
    for (int g = 0; g < Gq; ++g) {
        const float* qp = qbuf + ((size_t)b*Hh + kv*Gq + g)*HD + dl*4;
        float4 x0 = *(const float4*)(qp);
        float4 x1 = *(const float4*)(qp + 64);
        x0.x *= SC2; x0.y *= SC2; x0.z *= SC2; x0.w *= SC2;
        x1.x *= SC2; x1.y *= SC2; x1.z *= SC2; x1.w *= SC2;
        qa[g] = x0; qb[g] = x1;
    }

    const float* kbase = cache_k + ((size_t)b*HKVh + kv)*MAXLEN*HD;
    const float* vbase = cache_v + ((size_t)b*HKVh + kv)*MAXLEN*HD;

    // this wave's contiguous stripe
    const int nw  = (per + 7) >> 3;
    const int wp0 = p0 + wave * nw;
    const int wp1 = min(p1, wp0 + nw);

    float  m[Gq], l[Gq];
    float4 acc0[Gq], acc1[Gq];
#pragma unroll
    for (int g = 0; g < Gq; ++g) {
        m[g] = -1e30f; l[g] = 0.f;
        acc0[g] = make_float4(0.f,0.f,0.f,0.f);
        acc1[g] = make_float4(0.f,0.f,0.f,0.f);
    }

    for (int pp = wp0; pp < wp1; pp += 8) {
        const int pA = pp + sg;         // uniform within each 16-group
        const int pB = pp + 4 + sg;
        const bool vA = pA < wp1;
        const bool vB = pB < wp1;
        const int cA = vA ? pA : wp0;
        const int cB = vB ? pB : wp0;
        const float* krA = kbase + (size_t)cA*HD + dl*4;
        const float* krB = kbase + (size_t)cB*HD + dl*4;
        const float* vrA = vbase + (size_t)cA*HD + dl*4;
        const float* vrB = vbase + (size_t)cB*HD + dl*4;
        // issue all 8 loads up front (4 KB/wave in flight)
        const float4 ka0 = *(const float4*)(krA);
        const float4 ka1 = *(const float4*)(krA + 64);
        const float4 kb0 = *(const float4*)(krB);
        const float4 kb1 = *(const float4*)(krB + 64);
        const float4 va0 = *(const float4*)(vrA);
        const float4 va1 = *(const float4*)(vrA + 64);
        const float4 vb0 = *(const float4*)(vrB);
        const float4 vb1 = *(const float4*)(vrB + 64);

        float sA[Gq], sB[Gq];
#pragma unroll
        for (int g = 0; g < Gq; ++g) {
            float a = qa[g].x*ka0.x + qa[g].y*ka0.y + qa[g].z*ka0.z + qa[g].w*ka0.w;
            a = fmaf(qb[g].x, ka1.x, a); a = fmaf(qb[g].y, ka1.y, a);
            a = fmaf(qb[g].z, ka1.z, a); a = fmaf(qb[g].w, ka1.w, a);
            sA[g] = red16(a);
            float bq = qa[g].x*kb0.x + qa[g].y*kb0.y + qa[g].z*kb0.z + qa[g].w*kb0.w;
            bq = fmaf(qb[g].x, kb1.x, bq); bq = fmaf(qb[g].y, kb1.y, bq);
            bq = fmaf(qb[g].z, kb1.z, bq); bq = fmaf(qb[g].w, kb1.w, bq);
            sB[g] = red16(bq);
        }
        if (!vA) { sA[0] = -INFINITY; sA[1] = -INFINITY; sA[2] = -INFINITY; sA[3] = -INFINITY; }
        if (!vB) { sB[0] = -INFINITY; sB[1] = -INFINITY; sB[2] = -INFINITY; sB[3] = -INFINITY; }

        // online update, position A then B (branchless; exp2 domain)
#pragma unroll
        for (int g = 0; g < Gq; ++g) {
            float mn = fmaxf(m[g], sA[g]);
            float al = fast_exp2(m[g] - mn);
            float e  = fast_exp2(sA[g] - mn);
            m[g] = mn;
            l[g] = fmaf(l[g], al, e);
            acc0[g].x = fmaf(e, va0.x, acc0[g].x*al);
            acc0[g].y = fmaf(e, va0.y, acc0[g].y*al);
            acc0[g].z = fmaf(e, va0.z, acc0[g].z*al);
            acc0[g].w = fmaf(e, va0.w, acc0[g].w*al);
            acc1[g].x = fmaf(e, va1.x, acc1[g].x*al);
            acc1[g].y = fmaf(e, va1.y, acc1[g].y*al);
            acc1[g].z = fmaf(e, va1.z, acc1[g].z*al);
            acc1[g].w = fmaf(e, va1.w, acc1[g].w*al);
        }
#pragma unroll
        for (int g = 0; g < Gq; ++g) {
            float mn = fmaxf(m[g], sB[g]);
            float al = fast_exp2(m[g] - mn);
            float e  = fast_exp2(sB[g] - mn);
            m[g] = mn;
            l[g] = fmaf(l[g], al, e);
            acc0[g].x = fmaf(e, vb0.x, acc0[g].x*al);
            acc0[g].y = fmaf(e, vb0.y, acc0[g].y*al);
            acc0[g].z = fmaf(e, vb0.z, acc0[g].z*al);
            acc0[g].w = fmaf(e, vb0.w, acc0[g].w*al);
            acc1[g].x = fmaf(e, vb1.x, acc1[g].x*al);
            acc1[g].y = fmaf(e, vb1.y, acc1[g].y*al);
            acc1[g].z = fmaf(e, vb1.z, acc1[g].z*al);
            acc1[g].w = fmaf(e, vb1.w, acc1[g].w*al);
        }
    }

    // merge the 4 subgroup partials within the wave (xor16 then xor32)
#pragma unroll
    for (int g = 0; g < Gq; ++g) {
#pragma unroll
        for (int st = 0; st < 2; ++st) {
            const int off = st ? 32 : 16;
            float mo = __shfl_xor(m[g], off);
            float lo = __shfl_xor(l[g], off);
            float o0x = __shfl_xor(acc0[g].x, off);
            float o0y = __shfl_xor(acc0[g].y, off);
            float o0z = __shfl_xor(acc0[g].z, off);
            float o0w = __shfl_xor(acc0[g].w, off);
            float o1x = __shfl_xor(acc1[g].x, off);
            float o1y = __shfl_xor(acc1[g].y, off);
            float o1z = __shfl_xor(acc1[g].z, off);
            float o1w = __shfl_xor(acc1[g].w, off);
            float mn = fmaxf(m[g], mo);
            float w0 = fast_exp2(m[g] - mn);
            float w1 = fast_exp2(mo - mn);
            m[g] = mn;
            l[g] = l[g]*w0 + lo*w1;
            acc0[g].x = acc0[g].x*w0 + o0x*w1;
            acc0[g].y = acc0[g].y*w0 + o0y*w1;
            acc0[g].z = acc0[g].z*w0 + o0z*w1;
            acc0[g].w = acc0[g].w*w0 + o0w*w1;
            acc1[g].x = acc1[g].x*w0 + o1x*w1;
            acc1[g].y = acc1[g].y*w0 + o1y*w1;
            acc1[g].z = acc1[g].z*w0 + o1z*w1;
            acc1[g].w = acc1[g].w*w0 + o1w*w1;
        }
    }

    // stash wave partials in LDS (lanes 0..15 hold the full merged state per d-slice)
    if (lane < 16) {
#pragma unroll
        for (int g = 0; g < Gq; ++g) {
            *(float4*)(&sacc[wave][g][dl*4])      = acc0[g];
            *(float4*)(&sacc[wave][g][64 + dl*4]) = acc1[g];
        }
        if (lane == 0) {
#pragma unroll
            for (int g = 0; g < Gq; ++g) { sm[wave][g] = m[g]; sl[wave][g] = l[g]; }
        }
    }
    __syncthreads();

    // final block combine: 512 threads -> one (g, d) each
    {
        const int g = t >> 7, d = t & 127;
        float M = -1e30f;
#pragma unroll
        for (int w = 0; w < 8; ++w) M = fmaxf(M, sm[w][g]);
        float num = 0.f, den = 0.f;
#pragma unroll
        for (int w = 0; w < 8; ++w) {
            float wt = fast_exp2(sm[w][g] - M);
            num = fmaf(wt, sacc[w][g][d], num);
            den = fmaf(wt, sl[w][g], den);
        }
        float* po = pout + (size_t)(bk * LSPLIT + sp) * (Gq*HD + 2*Gq);
        po[g*HD + d] = num;
        if (d == 0) { po[Gq*HD + g] = M; po[Gq*HD + Gq + g] = den; }
    }
}

// ---------- Kernel 4: combine L-splits -> attn_out [b][h][d] (exp2 domain) ----------
__global__ __launch_bounds__(256) void k_comb(const float* __restrict__ pout,
    float* __restrict__ attn)
{
    int idx = blockIdx.x*256 + threadIdx.x;   // 131072
    int d = idx & 127;
    int h = (idx >> 7) & 31;
    int b = idx >> 12;
    int kv = h >> 2, g = h & 3;
    int bk = b*8 + kv;
    const float* base = pout + (size_t)bk * LSPLIT * (Gq*HD + 2*Gq);
    float m = -INFINITY;
#pragma unroll
    for (int s = 0; s < LSPLIT; ++s) m = fmaxf(m, base[s*520 + 512 + g]);
    float num = 0.f, den = 0.f;
#pragma unroll
    for (int s = 0; s < LSPLIT; ++s) {
        float ms = base[s*520 + 512 + g];
        float ls = base[s*520 + 516 + g];
        float w = (ms == -INFINITY) ? 0.f : fast_exp2(ms - m);
        num = fmaf(w, base[s*520 + g*HD + d], num);
        den = fmaf(w, ls, den);
    }
    attn[idx] = num / den;
}

// ---------- Kernel 5: out-projection split-K partial: part[ks][b][4096] ----------
__global__ __launch_bounds__(256) void k_proj(const float* __restrict__ inp,
    const float* __restrict__ W, float* __restrict__ part)
{
    __shared__ float xs[Bb][KCH];
    const int ct = blockIdx.x;      // 0..63
    const int ks = blockIdx.y;
    const int c0 = ct * 64;
    const int k0 = ks * KCH;

    const int t = threadIdx.x;
    for (int i = t; i < Bb * (KCH/4); i += 256) {
        int b = i >> 7;
        int kk = (i & 127) << 2;
        float4 v4 = *(const float4*)(inp + (size_t)b*NQ + k0 + kk);
        xs[b][kk+0] = v4.x; xs[b][kk+1] = v4.y; xs[b][kk+2] = v4.z; xs[b][kk+3] = v4.w;
    }
    __syncthreads();

    const int cg = t & 15;
    const int bg = t >> 4;
    const int b0 = bg * 2;
    const float* wp = W + (size_t)k0 * NQ + c0 + cg*4;
    float4 a0 = make_float4(0.f,0.f,0.f,0.f), a1 = make_float4(0.f,0.f,0.f,0.f);
#pragma unroll 2
    for (int k = 0; k < KCH; k += 4) {
        float4 w0 = *(const float4*)(wp);
        float4 w1 = *(const float4*)(wp + NQ);
        float4 w2 = *(const float4*)(wp + 2*NQ);
        float4 w3 = *(const float4*)(wp + 3*NQ);
        wp += 4*NQ;
        float4 xa = *(const float4*)(&xs[b0][k]);
        float4 xb = *(const float4*)(&xs[b0+1][k]);
        a0 = fma4(xa.x, w0, a0); a1 = fma4(xb.x, w0, a1);
        a0 = fma4(xa.y, w1, a0); a1 = fma4(xb.y, w1, a1);
        a0 = fma4(xa.z, w2, a0); a1 = fma4(xb.z, w2, a1);
        a0 = fma4(xa.w, w3, a0); a1 = fma4(xb.w, w3, a1);
    }
    size_t base = ((size_t)ks * Bb + b0) * NQ + c0 + cg*4;
    *(float4*)(part + base) = a0;
    *(float4*)(part + base + NQ) = a1;
}

// ---------- Kernel 6: reduce proj partials -> d_out ----------
__global__ __launch_bounds__(256) void k_red(const float* __restrict__ part,
    float* __restrict__ out)
{
    int idx = blockIdx.x*256 + threadIdx.x;   // 131072
    float s = 0.f;
#pragma unroll
    for (int k = 0; k < KSPLIT; ++k) s += part[(size_t)k*Bb*NQ + idx];
    out[idx] = s;
}

extern "C" void kernel_launch(void* const* d_in, const int* in_sizes, int n_in,
                              void* d_out, int out_size, void* d_ws, size_t ws_size,
                              hipStream_t stream)
{
    const float* x  = (const float*)d_in[0];
    float* cache_k  = (float*)d_in[1];
    float* cache_v  = (float*)d_in[2];
    const float* wq = (const float*)d_in[3];
    const float* wk = (const float*)d_in[4];
    const float* wv = (const float*)d_in[5];
    const float* wo = (const float*)d_in[6];
    const float* fc = (const float*)d_in[7];
    const float* fs = (const float*)d_in[8];
    const int* sp   = (const int*)d_in[9];
    float* out      = (float*)d_out;

    float* ws = (float*)d_ws;
    float* qkv_part = ws;                       // 8*32*6144   = 1572864 f
    float* qbuf     = qkv_part + 1572864;       // 32*32*128   = 131072 f
    float* attn_prt = qbuf + 131072;            // 256*4*520   = 532480 f
    float* attn_out = attn_prt + 532480;        // 131072 f
    float* proj_prt = attn_out + 131072;        // 8*32*4096   = 1048576 f

    k_qkv<<<dim3(96, 8), 256, 0, stream>>>(x, wq, wk, wv, qkv_part);
    k_rope_scatter<<<dim3(384), 256, 0, stream>>>(qkv_part, fc, fs, sp, qbuf, cache_k, cache_v);
    k_attn<<<dim3(256, LSPLIT), 512, 0, stream>>>(qbuf, cache_k, cache_v, sp, attn_prt);
    k_comb<<<dim3(512), 256, 0, stream>>>(attn_prt, attn_out);
    k_proj<<<dim3(64, 8), 256, 0, stream>>>(attn_out, wo, proj_prt);
    k_red<<<dim3(512), 256, 0, stream>>>(proj_prt, out);
}